// Round 7
// baseline (298.082 us; speedup 1.0000x reference)
//
#include <hip/hip_runtime.h>

#define SEQ 4096
#define DIM 1024
#define NH 16
#define HD 64
#define QKVSTR 3072

typedef __attribute__((ext_vector_type(8))) short bf16x8;
typedef __attribute__((ext_vector_type(4))) float f32x4;
typedef __attribute__((ext_vector_type(16))) float f32x16;
typedef __attribute__((ext_vector_type(4))) unsigned int uint4v;

__device__ __forceinline__ unsigned short f2bf(float f) {
  unsigned int b = __float_as_uint(f);
  b = b + 0x7fffu + ((b >> 16) & 1u);
  return (unsigned short)(b >> 16);
}

__device__ __forceinline__ unsigned int cvt_pk_bf16(float lo, float hi) {
  unsigned int r;
  asm("v_cvt_pk_bf16_f32 %0, %1, %2" : "=v"(r) : "v"(lo), "v"(hi));
  return r;
}

__device__ __forceinline__ float fast_exp2(float x) {
#if __has_builtin(__builtin_amdgcn_exp2f)
  return __builtin_amdgcn_exp2f(x);
#else
  float r; asm("v_exp_f32 %0, %1" : "=v"(r) : "v"(x)); return r;
#endif
}

typedef __attribute__((address_space(3))) unsigned int lds_uint;
typedef __attribute__((address_space(1))) const unsigned int global_uint;

__device__ __forceinline__ void gload_lds16(const void* g, void* l) {
  __builtin_amdgcn_global_load_lds((global_uint*)g, (lds_uint*)l, 16, 0, 0);
}

// ---------------- fused cast fp32 -> bf16 for all 5 tensors (1 launch) ----------------
__global__ __launch_bounds__(256) void cast_all_kernel(
    const float* __restrict__ X, const float* __restrict__ wq, const float* __restrict__ wk,
    const float* __restrict__ wv, const float* __restrict__ wo,
    unsigned short* __restrict__ Xb, unsigned short* __restrict__ Wqkv,
    unsigned short* __restrict__ Wob, float qscale) {
  int i = blockIdx.x * 256 + threadIdx.x;
  const float* src;
  unsigned short* dst;
  float sc = 1.f;
  if (i < 524288) { src = X + (size_t)i * 8; dst = Xb + (size_t)i * 8; }
  else if (i < 655360) { int j = i - 524288; src = wq + (size_t)j * 8; dst = Wqkv + (size_t)j * 8; sc = qscale; }
  else if (i < 786432) { int j = i - 655360; src = wk + (size_t)j * 8; dst = Wqkv + 1048576 + (size_t)j * 8; }
  else if (i < 917504) { int j = i - 786432; src = wv + (size_t)j * 8; dst = Wqkv + 2097152 + (size_t)j * 8; }
  else { int j = i - 917504; src = wo + (size_t)j * 8; dst = Wob + (size_t)j * 8; }
  const float4* p = (const float4*)src;
  float4 x0 = p[0], x1 = p[1];
  union { unsigned short u[8]; uint4v v; } o;
  o.u[0] = f2bf(x0.x * sc); o.u[1] = f2bf(x0.y * sc);
  o.u[2] = f2bf(x0.z * sc); o.u[3] = f2bf(x0.w * sc);
  o.u[4] = f2bf(x1.x * sc); o.u[5] = f2bf(x1.y * sc);
  o.u[6] = f2bf(x1.z * sc); o.u[7] = f2bf(x1.w * sc);
  *(uint4v*)dst = o.v;
}

// ---------------- GEMM: C[M,N] = A[M,K](bf16) @ B[N,K]^T(bf16) (+bias) ----------------
template<int BIASMODE, int OUT_F32>
__global__ __launch_bounds__(256) void gemm_bt_kernel(
    const unsigned short* __restrict__ A, const unsigned short* __restrict__ B,
    const float* __restrict__ b0, const float* __restrict__ b1, float qscale,
    void* __restrict__ Cout, int M, int N, int K) {
  __shared__ unsigned short As[128 * 32];
  __shared__ unsigned short Bs[128 * 32];
  int tid = threadIdx.x;
  int wave = tid >> 6, lane = tid & 63;
  int g = lane >> 4, lc = lane & 15;
  int wm = wave >> 1, wn = wave & 1;
  int m0 = blockIdx.y * 128, n0 = blockIdx.x * 128;

  f32x4 acc[4][4] = {};

  for (int k0 = 0; k0 < K; k0 += 32) {
    __syncthreads();
    for (int c = 0; c < 2; ++c) {
      int chunk = c * 256 + wave * 64 + lane;
      int row = chunk >> 2, cb = chunk & 3;
      gload_lds16(A + (size_t)(m0 + row) * K + k0 + cb * 8, As + (c * 256 + wave * 64) * 8);
      gload_lds16(B + (size_t)(n0 + row) * K + k0 + cb * 8, Bs + (c * 256 + wave * 64) * 8);
    }
    __syncthreads();
    bf16x8 af[4], bfr[4];
    for (int mf = 0; mf < 4; ++mf)
      af[mf] = *(const bf16x8*)&As[(wm * 64 + mf * 16 + lc) * 32 + g * 8];
    for (int nf = 0; nf < 4; ++nf)
      bfr[nf] = *(const bf16x8*)&Bs[(wn * 64 + nf * 16 + lc) * 32 + g * 8];
    for (int mf = 0; mf < 4; ++mf)
      for (int nf = 0; nf < 4; ++nf)
        acc[mf][nf] = __builtin_amdgcn_mfma_f32_16x16x32_bf16(af[mf], bfr[nf], acc[mf][nf], 0, 0, 0);
  }

  for (int nf = 0; nf < 4; ++nf) {
    int col = n0 + wn * 64 + nf * 16 + lc;
    float bias = 0.f;
    if (BIASMODE == 1) {
      int sect = col >> 10, cc = col & 1023;
      bias = (sect == 0) ? b0[cc] * qscale : ((sect == 2) ? b1[cc] : 0.f);
    } else if (BIASMODE == 2) {
      bias = b0[col];
    }
    for (int mf = 0; mf < 4; ++mf) {
      int row = m0 + wm * 64 + mf * 16 + g * 4;
      for (int r = 0; r < 4; ++r) {
        float v = acc[mf][nf][r] + bias;
        if (OUT_F32) ((float*)Cout)[(size_t)(row + r) * N + col] = v;
        else ((unsigned short*)Cout)[(size_t)(row + r) * N + col] = f2bf(v);
      }
    }
  }
}

// ---------------- V transpose: V (rows of QKV, stride 3072) -> Vt[D][S] ----------------
__global__ __launch_bounds__(256) void transpose_kernel(
    const unsigned short* __restrict__ V, unsigned short* __restrict__ Vt) {
  __shared__ unsigned short Ts[64 * 72];
  int tid = threadIdx.x;
  int s0 = blockIdx.x * 64, d0 = blockIdx.y * 64;
  for (int c = 0; c < 2; ++c) {
    int q = c * 256 + tid;
    int r = q >> 3, cb = q & 7;
    uint4v v = *(const uint4v*)&V[(size_t)(s0 + r) * QKVSTR + d0 + cb * 8];
    *(uint4v*)&Ts[r * 72 + cb * 8] = v;
  }
  __syncthreads();
  for (int c = 0; c < 2; ++c) {
    int q = c * 256 + tid;
    int d = q >> 3, sc = q & 7;
    union { unsigned short u[8]; uint4v v; } ov;
    for (int j = 0; j < 8; ++j) ov.u[j] = Ts[(sc * 8 + j) * 72 + d];
    *(uint4v*)&Vt[(size_t)(d0 + d) * SEQ + s0 + sc * 8] = ov.v;
  }
}

// ---------------- flash attention: 8-wave kv-split x2, swapped-QK 32x32 ----------------
// Waves 0-3 (grp 0) do kv tiles 0..31, waves 4-7 (grp 1) do 32..63 over a shared
// Q tile. No-max softmax -> halves combine by pure addition (exact). Per-tile
// sync structure is the R4-proven template: 2 bufs, 2 barriers, counted vmcnt(4).
// Hoisted LDS read offsets (kf/vf share offb[4]; f=1 = +4096B; buffer via 2x unroll).
__global__ __launch_bounds__(512, 4) void attn_kernel(
    const unsigned short* __restrict__ QKV, const unsigned short* __restrict__ Vt,
    unsigned short* __restrict__ Aout) {
  __shared__ unsigned short Qs[128 * 64];        // 16 KB
  __shared__ unsigned short Ks[2][2][64 * 64];   // [grp][buf] 32 KB
  __shared__ unsigned short Vs[2][2][64 * 64];   // 32 KB
  int tid = threadIdx.x;
  int w = tid >> 6, lane = tid & 63;
  int hi = lane >> 5, l31 = lane & 31;
  int qw = w & 3, grp = w >> 2;

  // XCD swizzle: 512 blocks, 8 XCDs -> XCD x owns heads 2x..2x+1 (K/V fit 4MB L2)
  int bid = blockIdx.x;
  int swz = (bid & 7) * 64 + (bid >> 3);
  int h = swz >> 5;
  int q0 = (swz & 31) * 128;

  const unsigned short* Qg = QKV + h * HD;
  const unsigned short* Kg = QKV + DIM + h * HD;
  const unsigned short* Vg = Vt + (size_t)(h * HD) * SEQ;
  int kvbase = grp * (SEQ / 2);

  // staging offsets: 4 waves of each group stage the group's K/V tile
  int ch0 = qw * 64 + lane;
  int r0s = ch0 >> 3, d0s = (ch0 & 7) ^ (r0s & 7);
  int ch1 = 256 + ch0;
  int r1s = ch1 >> 3, d1s = (ch1 & 7) ^ (r1s & 7);
  size_t koff0 = (size_t)r0s * QKVSTR + d0s * 8;
  size_t koff1 = (size_t)r1s * QKVSTR + d1s * 8;
  size_t voff0 = (size_t)r0s * SEQ + d0s * 8;
  size_t voff1 = (size_t)r1s * SEQ + d1s * 8;
  unsigned short* sKlo[2] = { &Ks[grp][0][(qw * 64) * 8],       &Ks[grp][1][(qw * 64) * 8] };
  unsigned short* sKhi[2] = { &Ks[grp][0][(256 + qw * 64) * 8], &Ks[grp][1][(256 + qw * 64) * 8] };
  unsigned short* sVlo[2] = { &Vs[grp][0][(qw * 64) * 8],       &Vs[grp][1][(qw * 64) * 8] };
  unsigned short* sVhi[2] = { &Vs[grp][0][(256 + qw * 64) * 8], &Vs[grp][1][(256 + qw * 64) * 8] };

  // stage Q [128][64]: 1024 chunks by 8 waves, XOR-swizzled via global source
  for (int c = 0; c < 2; ++c) {
    int chunk = c * 512 + w * 64 + lane;
    int row = chunk >> 3, pos = chunk & 7;
    int db = pos ^ (row & 7);
    gload_lds16(Qg + (size_t)(q0 + row) * QKVSTR + db * 8, Qs + (c * 512 + w * 64) * 8);
  }
  // stage this group's K/V tile 0
  {
    const unsigned short* Kt = Kg + (size_t)kvbase * QKVSTR;
    const unsigned short* Vtt = Vg + kvbase;
    gload_lds16(Kt + koff0, sKlo[0]);
    gload_lds16(Kt + koff1, sKhi[0]);
    gload_lds16(Vtt + voff0, sVlo[0]);
    gload_lds16(Vtt + voff1, sVhi[0]);
  }
  asm volatile("s_waitcnt vmcnt(4)" ::: "memory");  // Q landed; tile0 in flight
  __builtin_amdgcn_sched_barrier(0);
  __builtin_amdgcn_s_barrier();

  // Q fragments (B-operand: col q = l31, k = d); both groups read same q-rows
  bf16x8 qf[4];
  {
    int qrow = qw * 32 + l31;
    for (int dc = 0; dc < 4; ++dc) {
      int pos = 2 * dc + hi;
      qf[dc] = *(const bf16x8*)&Qs[qrow * 64 + (pos ^ (qrow & 7)) * 8];
    }
  }

  // hoisted LDS byte offsets for kf/vf (same formula; f=1 row+32 keeps &7 -> +4096B imm)
  int offb[4];
#pragma unroll
  for (int dc = 0; dc < 4; ++dc)
    offb[dc] = l31 * 128 + (((2 * dc + hi) ^ (l31 & 7)) * 16);
  const char* KbA = (const char*)&Ks[grp][0][0];
  const char* KbB = (const char*)&Ks[grp][1][0];
  const char* VbA = (const char*)&Vs[grp][0][0];
  const char* VbB = (const char*)&Vs[grp][1][0];

  f32x16 o0 = {}, o1 = {};
  float la0 = 0.f, la1 = 0.f, la2 = 0.f, la3 = 0.f;

  auto body = [&](int t, int CUR) {
    int NB = CUR ^ 1;
    // prefetch this group's tile t+1 (wraps within half; vmcnt invariant)
    int kvn = kvbase + (((t + 1) & 31) << 6);
    const unsigned short* Kt = Kg + (size_t)kvn * QKVSTR;
    const unsigned short* Vtt = Vg + kvn;
    gload_lds16(Kt + koff0, sKlo[NB]);
    gload_lds16(Kt + koff1, sKhi[NB]);
    gload_lds16(Vtt + voff0, sVlo[NB]);
    gload_lds16(Vtt + voff1, sVhi[NB]);
    asm volatile("s_waitcnt vmcnt(4)" ::: "memory");  // tile t resident (ours)
    __builtin_amdgcn_sched_barrier(0);
    __builtin_amdgcn_s_barrier();                     // tile t resident (all waves)
    __builtin_amdgcn_sched_barrier(0);

    const char* Kb = CUR ? KbB : KbA;
    const char* Vb = CUR ? VbB : VbA;
    bf16x8 kf0[4], kf1[4];
#pragma unroll
    for (int dc = 0; dc < 4; ++dc) {
      kf0[dc] = *(const bf16x8*)(Kb + offb[dc]);
      kf1[dc] = *(const bf16x8*)(Kb + offb[dc] + 4096);
    }
    f32x16 st0 = {}, st1 = {};
    __builtin_amdgcn_s_setprio(1);
#pragma unroll
    for (int dc = 0; dc < 4; ++dc) {
      st0 = __builtin_amdgcn_mfma_f32_32x32x16_bf16(kf0[dc], qf[dc], st0, 0, 0, 0);
      st1 = __builtin_amdgcn_mfma_f32_32x32x16_bf16(kf1[dc], qf[dc], st1, 0, 0, 0);
    }
    __builtin_amdgcn_s_setprio(0);

    // V fragments early (latency hides under exp/pack)
    bf16x8 vf0[4], vf1[4];
#pragma unroll
    for (int c = 0; c < 4; ++c) {
      vf0[c] = *(const bf16x8*)(Vb + offb[c]);
      vf1[c] = *(const bf16x8*)(Vb + offb[c] + 4096);
    }

    // P = exp2(S^T); 4 independent lsum accumulators (break dep chain)
    float p0[16], p1[16];
#pragma unroll
    for (int r = 0; r < 16; r += 4) {
      p0[r] = fast_exp2(st0[r]); p0[r + 1] = fast_exp2(st0[r + 1]);
      p0[r + 2] = fast_exp2(st0[r + 2]); p0[r + 3] = fast_exp2(st0[r + 3]);
      la0 += p0[r]; la1 += p0[r + 1]; la2 += p0[r + 2]; la3 += p0[r + 3];
    }
#pragma unroll
    for (int r = 0; r < 16; r += 4) {
      p1[r] = fast_exp2(st1[r]); p1[r + 1] = fast_exp2(st1[r + 1]);
      p1[r + 2] = fast_exp2(st1[r + 2]); p1[r + 3] = fast_exp2(st1[r + 3]);
      la0 += p1[r]; la1 += p1[r + 1]; la2 += p1[r + 2]; la3 += p1[r + 3];
    }

    // pack to bf16 + permlane32_swap -> PV A-frags pa[c] (T12)
    bf16x8 pa[4];
#pragma unroll
    for (int f = 0; f < 2; ++f) {
      const float* pp = f ? p1 : p0;
#pragma unroll
      for (int cc = 0; cc < 2; ++cc) {
        unsigned uLO0 = cvt_pk_bf16(pp[8 * cc + 0], pp[8 * cc + 1]);
        unsigned uLO1 = cvt_pk_bf16(pp[8 * cc + 2], pp[8 * cc + 3]);
        unsigned uHI0 = cvt_pk_bf16(pp[8 * cc + 4], pp[8 * cc + 5]);
        unsigned uHI1 = cvt_pk_bf16(pp[8 * cc + 6], pp[8 * cc + 7]);
        auto s0 = __builtin_amdgcn_permlane32_swap(uLO0, uHI0, false, false);
        auto s1 = __builtin_amdgcn_permlane32_swap(uLO1, uHI1, false, false);
        union { unsigned u[4]; bf16x8 v; } pw;
        pw.u[0] = s0[0]; pw.u[1] = s1[0]; pw.u[2] = s0[1]; pw.u[3] = s1[1];
        pa[f * 2 + cc] = pw.v;
      }
    }

    // PV
    __builtin_amdgcn_s_setprio(1);
#pragma unroll
    for (int c = 0; c < 4; ++c) {
      o0 = __builtin_amdgcn_mfma_f32_32x32x16_bf16(pa[c], vf0[c], o0, 0, 0, 0);
      o1 = __builtin_amdgcn_mfma_f32_32x32x16_bf16(pa[c], vf1[c], o1, 0, 0, 0);
    }
    __builtin_amdgcn_s_setprio(0);

    asm volatile("" ::: "memory");
    __builtin_amdgcn_sched_barrier(0);
    __builtin_amdgcn_s_barrier();   // reads of tile t done -> next stage may overwrite
  };

  for (int tt = 0; tt < 32; tt += 2) {
    body(tt + 0, 0);
    body(tt + 1, 1);
  }

  // per-half lsum finalize (cross-hi reduce)
  float lsum = (la0 + la1) + (la2 + la3);
  lsum += __shfl_xor(lsum, 32);

  // combine halves via LDS (exact: no-max softmax partials are additive)
  __syncthreads();  // drains wrap-prefetch vmcnt; all tile reads done
  float* cbO0 = (float*)&Ks[0][0][0];  // 32 KB
  float* cbO1 = (float*)&Vs[0][0][0];  // 32 KB
  float* cbL  = (float*)&Qs[0];        // 1 KB of 16
  int cbase = (qw * 64 + lane) * 32;
  int lx = lane & 31;
  if (grp == 1) {
#pragma unroll
    for (int r = 0; r < 16; ++r) {
      cbO0[cbase + (r ^ lx)] = o0[r];
      cbO1[cbase + (r ^ lx)] = o1[r];
    }
    cbL[qw * 64 + lane] = lsum;
  }
  __syncthreads();
  if (grp == 0) {
#pragma unroll
    for (int r = 0; r < 16; ++r) {
      o0[r] += cbO0[cbase + (r ^ lx)];
      o1[r] += cbO1[cbase + (r ^ lx)];
    }
    lsum += cbL[qw * 64 + lane];
    float inv = 1.f / lsum;
#pragma unroll
    for (int r = 0; r < 16; ++r) {
      int qr = (r & 3) + 8 * (r >> 2) + 4 * hi;
      float ir = __shfl(inv, qr + (lane & 32));
      size_t row = q0 + qw * 32 + qr;
      Aout[row * DIM + h * HD + l31]      = f2bf(o0[r] * ir);
      Aout[row * DIM + h * HD + 32 + l31] = f2bf(o1[r] * ir);
    }
  }
}

extern "C" void kernel_launch(void* const* d_in, const int* in_sizes, int n_in,
                              void* d_out, int out_size, void* d_ws, size_t ws_size,
                              hipStream_t stream) {
  (void)in_sizes; (void)n_in; (void)out_size; (void)ws_size;
  const float* X  = (const float*)d_in[0];
  const float* wq = (const float*)d_in[1];
  const float* bq = (const float*)d_in[2];
  const float* wk = (const float*)d_in[3];
  const float* wv = (const float*)d_in[4];
  const float* bv = (const float*)d_in[5];
  const float* wo = (const float*)d_in[6];
  const float* bo = (const float*)d_in[7];

  char* ws = (char*)d_ws;
  const size_t SZ_XD  = (size_t)SEQ * DIM * 2;      // 8 MB
  const size_t SZ_W   = (size_t)DIM * DIM * 2;      // 2 MB
  const size_t SZ_QKV = (size_t)SEQ * QKVSTR * 2;   // 24 MB
  unsigned short* Xb   = (unsigned short*)(ws);                    // reused as Ab
  unsigned short* Wqkv = (unsigned short*)(ws + SZ_XD);            // [3072][1024]
  unsigned short* Wob  = (unsigned short*)(ws + SZ_XD + 3 * SZ_W);
  unsigned short* QKVb = (unsigned short*)(ws + SZ_XD + 4 * SZ_W); // [4096][3072]
  unsigned short* Vtb  = (unsigned short*)(ws + SZ_XD + 4 * SZ_W + SZ_QKV);
  unsigned short* Ab   = Xb;

  const float QSCALE = 0.125f * 1.44269504088896f;  // fold 1/sqrt(hd) * log2(e) into Wq/bq

  // one fused cast launch: 1048576 groups of 8 -> 4096 blocks
  cast_all_kernel<<<4096, 256, 0, stream>>>(X, wq, wk, wv, wo, Xb, Wqkv, Wob, QSCALE);

  // fused QKV projection: [4096][3072] bf16
  gemm_bt_kernel<1, 0><<<dim3(QKVSTR / 128, SEQ / 128), 256, 0, stream>>>(
      Xb, Wqkv, bq, bv, QSCALE, QKVb, SEQ, QKVSTR, DIM);

  // V^T: [1024][4096]
  transpose_kernel<<<dim3(SEQ / 64, DIM / 64), 256, 0, stream>>>(QKVb + 2 * DIM, Vtb);

  attn_kernel<<<SEQ / 128 * NH, 512, 0, stream>>>(QKVb, Vtb, Ab);

  // output projection (f32 out)
  gemm_bt_kernel<2, 1><<<dim3(DIM / 128, SEQ / 128), 256, 0, stream>>>(
      Ab, Wob, bo, nullptr, 1.f, d_out, SEQ, DIM, DIM);
}

// Round 8
// 175.778 us; speedup vs baseline: 1.6958x; 1.6958x over previous
//
#include <hip/hip_runtime.h>

#define SEQ 4096
#define DIM 1024
#define NH 16
#define HD 64
#define QKVSTR 3072

typedef __attribute__((ext_vector_type(8))) short bf16x8;
typedef __attribute__((ext_vector_type(4))) float f32x4;
typedef __attribute__((ext_vector_type(16))) float f32x16;
typedef __attribute__((ext_vector_type(4))) unsigned int uint4v;

__device__ __forceinline__ unsigned short f2bf(float f) {
  unsigned int b = __float_as_uint(f);
  b = b + 0x7fffu + ((b >> 16) & 1u);
  return (unsigned short)(b >> 16);
}

__device__ __forceinline__ unsigned int cvt_pk_bf16(float lo, float hi) {
  unsigned int r;
  asm("v_cvt_pk_bf16_f32 %0, %1, %2" : "=v"(r) : "v"(lo), "v"(hi));
  return r;
}

__device__ __forceinline__ float fast_exp2(float x) {
#if __has_builtin(__builtin_amdgcn_exp2f)
  return __builtin_amdgcn_exp2f(x);
#else
  float r; asm("v_exp_f32 %0, %1" : "=v"(r) : "v"(x)); return r;
#endif
}

typedef __attribute__((address_space(3))) unsigned int lds_uint;
typedef __attribute__((address_space(1))) const unsigned int global_uint;

__device__ __forceinline__ void gload_lds16(const void* g, void* l) {
  __builtin_amdgcn_global_load_lds((global_uint*)g, (lds_uint*)l, 16, 0, 0);
}

// ---------------- fused cast fp32 -> bf16 for all 5 tensors (1 launch) ----------------
__global__ __launch_bounds__(256) void cast_all_kernel(
    const float* __restrict__ X, const float* __restrict__ wq, const float* __restrict__ wk,
    const float* __restrict__ wv, const float* __restrict__ wo,
    unsigned short* __restrict__ Xb, unsigned short* __restrict__ Wqkv,
    unsigned short* __restrict__ Wob, float qscale) {
  int i = blockIdx.x * 256 + threadIdx.x;
  const float* src;
  unsigned short* dst;
  float sc = 1.f;
  if (i < 524288) { src = X + (size_t)i * 8; dst = Xb + (size_t)i * 8; }
  else if (i < 655360) { int j = i - 524288; src = wq + (size_t)j * 8; dst = Wqkv + (size_t)j * 8; sc = qscale; }
  else if (i < 786432) { int j = i - 655360; src = wk + (size_t)j * 8; dst = Wqkv + 1048576 + (size_t)j * 8; }
  else if (i < 917504) { int j = i - 786432; src = wv + (size_t)j * 8; dst = Wqkv + 2097152 + (size_t)j * 8; }
  else { int j = i - 917504; src = wo + (size_t)j * 8; dst = Wob + (size_t)j * 8; }
  const float4* p = (const float4*)src;
  float4 x0 = p[0], x1 = p[1];
  union { unsigned short u[8]; uint4v v; } o;
  o.u[0] = f2bf(x0.x * sc); o.u[1] = f2bf(x0.y * sc);
  o.u[2] = f2bf(x0.z * sc); o.u[3] = f2bf(x0.w * sc);
  o.u[4] = f2bf(x1.x * sc); o.u[5] = f2bf(x1.y * sc);
  o.u[6] = f2bf(x1.z * sc); o.u[7] = f2bf(x1.w * sc);
  *(uint4v*)dst = o.v;
}

// ---------------- GEMM: C[M,N] = A[M,K](bf16) @ B[N,K]^T(bf16) (+bias) ----------------
template<int BIASMODE, int OUT_F32>
__global__ __launch_bounds__(256) void gemm_bt_kernel(
    const unsigned short* __restrict__ A, const unsigned short* __restrict__ B,
    const float* __restrict__ b0, const float* __restrict__ b1, float qscale,
    void* __restrict__ Cout, int M, int N, int K) {
  __shared__ unsigned short As[128 * 32];
  __shared__ unsigned short Bs[128 * 32];
  int tid = threadIdx.x;
  int wave = tid >> 6, lane = tid & 63;
  int g = lane >> 4, lc = lane & 15;
  int wm = wave >> 1, wn = wave & 1;
  int m0 = blockIdx.y * 128, n0 = blockIdx.x * 128;

  f32x4 acc[4][4] = {};

  for (int k0 = 0; k0 < K; k0 += 32) {
    __syncthreads();
    for (int c = 0; c < 2; ++c) {
      int chunk = c * 256 + wave * 64 + lane;
      int row = chunk >> 2, cb = chunk & 3;
      gload_lds16(A + (size_t)(m0 + row) * K + k0 + cb * 8, As + (c * 256 + wave * 64) * 8);
      gload_lds16(B + (size_t)(n0 + row) * K + k0 + cb * 8, Bs + (c * 256 + wave * 64) * 8);
    }
    __syncthreads();
    bf16x8 af[4], bfr[4];
    for (int mf = 0; mf < 4; ++mf)
      af[mf] = *(const bf16x8*)&As[(wm * 64 + mf * 16 + lc) * 32 + g * 8];
    for (int nf = 0; nf < 4; ++nf)
      bfr[nf] = *(const bf16x8*)&Bs[(wn * 64 + nf * 16 + lc) * 32 + g * 8];
    for (int mf = 0; mf < 4; ++mf)
      for (int nf = 0; nf < 4; ++nf)
        acc[mf][nf] = __builtin_amdgcn_mfma_f32_16x16x32_bf16(af[mf], bfr[nf], acc[mf][nf], 0, 0, 0);
  }

  for (int nf = 0; nf < 4; ++nf) {
    int col = n0 + wn * 64 + nf * 16 + lc;
    float bias = 0.f;
    if (BIASMODE == 1) {
      int sect = col >> 10, cc = col & 1023;
      bias = (sect == 0) ? b0[cc] * qscale : ((sect == 2) ? b1[cc] : 0.f);
    } else if (BIASMODE == 2) {
      bias = b0[col];
    }
    for (int mf = 0; mf < 4; ++mf) {
      int row = m0 + wm * 64 + mf * 16 + g * 4;
      for (int r = 0; r < 4; ++r) {
        float v = acc[mf][nf][r] + bias;
        if (OUT_F32) ((float*)Cout)[(size_t)(row + r) * N + col] = v;
        else ((unsigned short*)Cout)[(size_t)(row + r) * N + col] = f2bf(v);
      }
    }
  }
}

// ---------------- V transpose: V (rows of QKV, stride 3072) -> Vt[D][S] ----------------
__global__ __launch_bounds__(256) void transpose_kernel(
    const unsigned short* __restrict__ V, unsigned short* __restrict__ Vt) {
  __shared__ unsigned short Ts[64 * 72];
  int tid = threadIdx.x;
  int s0 = blockIdx.x * 64, d0 = blockIdx.y * 64;
  for (int c = 0; c < 2; ++c) {
    int q = c * 256 + tid;
    int r = q >> 3, cb = q & 7;
    uint4v v = *(const uint4v*)&V[(size_t)(s0 + r) * QKVSTR + d0 + cb * 8];
    *(uint4v*)&Ts[r * 72 + cb * 8] = v;
  }
  __syncthreads();
  for (int c = 0; c < 2; ++c) {
    int q = c * 256 + tid;
    int d = q >> 3, sc = q & 7;
    union { unsigned short u[8]; uint4v v; } ov;
    for (int j = 0; j < 8; ++j) ov.u[j] = Ts[(sc * 8 + j) * 72 + d];
    *(uint4v*)&Vt[(size_t)(d0 + d) * SEQ + s0 + sc * 8] = ov.v;
  }
}

// ---------------- flash attention: R6-proven 4-wave body, block-level kv-split x2 ----------------
// Grid 1024: (q-tile, head, half). Each block runs 32 kv tiles of its half with
// the proven 2-buf/2-barrier/vmcnt(4) template, then stores per-half-normalized
// o (bf16) + l (f32). No-max softmax -> halves combine exactly in combine_kernel.
// O0g: [4096][1024] (dead Xb region); O1g: QKVb+2048 (dead V-cols, stride 3072);
// Lg: [2][NH][SEQ] f32 (dead Wqkv region).
__global__ __launch_bounds__(256) void attn_kernel(
    const unsigned short* __restrict__ QKV, const unsigned short* __restrict__ Vt,
    unsigned short* __restrict__ O0g, unsigned short* __restrict__ O1g,
    float* __restrict__ Lg) {
  __shared__ unsigned short Qs[128 * 64];
  __shared__ unsigned short Ks[2][64 * 64];
  __shared__ unsigned short Vs[2][64 * 64];
  int tid = threadIdx.x;
  int w = tid >> 6, lane = tid & 63;
  int hi = lane >> 5, l31 = lane & 31;

  // XCD swizzle: 1024 blocks, 8 XCDs -> XCD x owns swz [128x,128x+128) = heads 2x..2x+1
  int bid = blockIdx.x;
  int swz = (bid & 7) * 128 + (bid >> 3);
  int h = swz >> 6;
  int q0 = ((swz >> 1) & 31) * 128;
  int hf = swz & 1;                 // kv half
  int kvbase = hf * (SEQ / 2);

  const unsigned short* Qg = QKV + h * HD;
  const unsigned short* Kg = QKV + DIM + h * HD;
  const unsigned short* Vg = Vt + (size_t)(h * HD) * SEQ;

  // loop-invariant per-lane staging offsets (chunk = c*256 + w*64 + lane)
  int ch0 = w * 64 + lane;
  int r0s = ch0 >> 3, d0s = (ch0 & 7) ^ (r0s & 7);
  int ch1 = 256 + ch0;
  int r1s = ch1 >> 3, d1s = (ch1 & 7) ^ (r1s & 7);
  size_t koff0 = (size_t)r0s * QKVSTR + d0s * 8;
  size_t koff1 = (size_t)r1s * QKVSTR + d1s * 8;
  size_t voff0 = (size_t)r0s * SEQ + d0s * 8;
  size_t voff1 = (size_t)r1s * SEQ + d1s * 8;
  unsigned short* ldsK_lo[2] = { &Ks[0][(w * 64) * 8],       &Ks[1][(w * 64) * 8] };
  unsigned short* ldsK_hi[2] = { &Ks[0][(256 + w * 64) * 8], &Ks[1][(256 + w * 64) * 8] };
  unsigned short* ldsV_lo[2] = { &Vs[0][(w * 64) * 8],       &Vs[1][(w * 64) * 8] };
  unsigned short* ldsV_hi[2] = { &Vs[0][(256 + w * 64) * 8], &Vs[1][(256 + w * 64) * 8] };

  // stage Q [128][64], XOR-swizzled via pre-swizzled global source (4 loads)
  for (int c = 0; c < 4; ++c) {
    int chunk = c * 256 + w * 64 + lane;
    int row = chunk >> 3, pos = chunk & 7;
    int db = pos ^ (row & 7);
    gload_lds16(Qg + (size_t)(q0 + row) * QKVSTR + db * 8, Qs + (c * 256 + w * 64) * 8);
  }
  // stage K/V tile 0 of this half (4 loads) -> 8 outstanding
  {
    const unsigned short* Kt = Kg + (size_t)kvbase * QKVSTR;
    const unsigned short* Vtt = Vg + kvbase;
    gload_lds16(Kt + koff0, ldsK_lo[0]);
    gload_lds16(Kt + koff1, ldsK_hi[0]);
    gload_lds16(Vtt + voff0, ldsV_lo[0]);
    gload_lds16(Vtt + voff1, ldsV_hi[0]);
  }
  asm volatile("s_waitcnt vmcnt(4)" ::: "memory");  // Q done; tile0 in flight
  __builtin_amdgcn_sched_barrier(0);
  __builtin_amdgcn_s_barrier();

  // Q fragments in registers (B-operand: col q = l31, k = d)
  bf16x8 qf[4];
  {
    int qrow = w * 32 + l31;
    for (int dc = 0; dc < 4; ++dc) {
      int pos = 2 * dc + hi;
      qf[dc] = *(const bf16x8*)&Qs[qrow * 64 + (pos ^ (qrow & 7)) * 8];
    }
  }

  f32x16 o0 = {}, o1 = {};
  float lsum = 0.f;
  int cur = 0;

  for (int t = 0; t < 32; ++t) {
    // prefetch tile t+1 (wraps within half to keep vmcnt invariant)
    {
      int kvn = kvbase + (((t + 1) & 31) << 6);
      const unsigned short* Kt = Kg + (size_t)kvn * QKVSTR;
      const unsigned short* Vtt = Vg + kvn;
      int nb = cur ^ 1;
      gload_lds16(Kt + koff0, ldsK_lo[nb]);
      gload_lds16(Kt + koff1, ldsK_hi[nb]);
      gload_lds16(Vtt + voff0, ldsV_lo[nb]);
      gload_lds16(Vtt + voff1, ldsV_hi[nb]);
    }
    asm volatile("s_waitcnt vmcnt(4)" ::: "memory");  // tile t resident (ours)
    __builtin_amdgcn_sched_barrier(0);
    __builtin_amdgcn_s_barrier();                     // tile t resident (all waves)
    __builtin_amdgcn_sched_barrier(0);

    // K fragments (A-operand: row kv = f*32+l31, k = d)
    bf16x8 kf[2][4];
    for (int f = 0; f < 2; ++f)
      for (int dc = 0; dc < 4; ++dc) {
        int krow = f * 32 + l31;
        int pos = 2 * dc + hi;
        kf[f][dc] = *(const bf16x8*)&Ks[cur][krow * 64 + (pos ^ (krow & 7)) * 8];
      }
    f32x16 st0 = {}, st1 = {};
    __builtin_amdgcn_s_setprio(1);
    for (int dc = 0; dc < 4; ++dc) {
      st0 = __builtin_amdgcn_mfma_f32_32x32x16_bf16(kf[0][dc], qf[dc], st0, 0, 0, 0);
      st1 = __builtin_amdgcn_mfma_f32_32x32x16_bf16(kf[1][dc], qf[dc], st1, 0, 0, 0);
    }
    __builtin_amdgcn_s_setprio(0);

    // V fragments early (latency hides under exp/pack)
    bf16x8 vf0[4], vf1[4];
#pragma unroll
    for (int c = 0; c < 4; ++c) {
      int pos = 2 * c + hi;
      int r0 = l31, r1 = 32 + l31;
      vf0[c] = *(const bf16x8*)&Vs[cur][r0 * 64 + (pos ^ (r0 & 7)) * 8];
      vf1[c] = *(const bf16x8*)&Vs[cur][r1 * 64 + (pos ^ (r1 & 7)) * 8];
    }

    // P = exp2(S^T) in-register; per-lane partial row-sum
    float p0[16], p1[16];
    float ls = 0.f;
#pragma unroll
    for (int r = 0; r < 16; ++r) { p0[r] = fast_exp2(st0[r]); ls += p0[r]; }
#pragma unroll
    for (int r = 0; r < 16; ++r) { p1[r] = fast_exp2(st1[r]); ls += p1[r]; }
    lsum += ls;

    // pack to bf16 + permlane32_swap -> PV A-frags pa[c] (T12)
    bf16x8 pa[4];
#pragma unroll
    for (int f = 0; f < 2; ++f) {
      const float* pp = f ? p1 : p0;
#pragma unroll
      for (int cc = 0; cc < 2; ++cc) {
        unsigned uLO0 = cvt_pk_bf16(pp[8 * cc + 0], pp[8 * cc + 1]);
        unsigned uLO1 = cvt_pk_bf16(pp[8 * cc + 2], pp[8 * cc + 3]);
        unsigned uHI0 = cvt_pk_bf16(pp[8 * cc + 4], pp[8 * cc + 5]);
        unsigned uHI1 = cvt_pk_bf16(pp[8 * cc + 6], pp[8 * cc + 7]);
        auto s0 = __builtin_amdgcn_permlane32_swap(uLO0, uHI0, false, false);
        auto s1 = __builtin_amdgcn_permlane32_swap(uLO1, uHI1, false, false);
        union { unsigned u[4]; bf16x8 v; } pw;
        pw.u[0] = s0[0]; pw.u[1] = s1[0]; pw.u[2] = s0[1]; pw.u[3] = s1[1];
        pa[f * 2 + cc] = pw.v;
      }
    }

    // PV
    __builtin_amdgcn_s_setprio(1);
#pragma unroll
    for (int c = 0; c < 4; ++c) {
      o0 = __builtin_amdgcn_mfma_f32_32x32x16_bf16(pa[c], vf0[c], o0, 0, 0, 0);
      o1 = __builtin_amdgcn_mfma_f32_32x32x16_bf16(pa[c], vf1[c], o1, 0, 0, 0);
    }
    __builtin_amdgcn_s_setprio(0);

    asm volatile("" ::: "memory");
    __builtin_amdgcn_sched_barrier(0);
    __builtin_amdgcn_s_barrier();   // all reads of tile t done -> next stage may overwrite
    cur ^= 1;
  }

  // epilogue: per-half l, per-half-normalized o -> partial stores
  lsum += __shfl_xor(lsum, 32);
  float inv = 1.f / lsum;  // valid for q = l31 (both halves)
  if (hi == 0)
    Lg[(hf * NH + h) * SEQ + q0 + w * 32 + l31] = lsum;
  unsigned short* Od = hf ? O1g : O0g;
  int ostr = hf ? QKVSTR : DIM;
#pragma unroll
  for (int r = 0; r < 16; ++r) {
    int qr = (r & 3) + 8 * (r >> 2) + 4 * hi;
    float ir = __shfl(inv, qr + (lane & 32));
    size_t row = q0 + w * 32 + qr;
    Od[row * ostr + h * HD + l31]      = f2bf(o0[r] * ir);
    Od[row * ostr + h * HD + 32 + l31] = f2bf(o1[r] * ir);
  }
}

// ---------------- combine halves: A <- w0*A + w1*P1 (in-place on A) ----------------
__global__ __launch_bounds__(256) void combine_kernel(
    unsigned short* __restrict__ A, const unsigned short* __restrict__ P1,
    const float* __restrict__ L) {
  int idx = blockIdx.x * 256 + threadIdx.x;  // 4096 * 128
  int row = idx >> 7, c8 = idx & 127;
  int col = c8 << 3, h = col >> 6;
  float l0 = L[h * SEQ + row];
  float l1 = L[(NH + h) * SEQ + row];
  float s = 1.f / (l0 + l1);
  float w0 = l0 * s, w1 = l1 * s;
  union { unsigned short u[8]; uint4v v; } a, b, o;
  a.v = *(const uint4v*)&A[(size_t)row * DIM + col];
  b.v = *(const uint4v*)&P1[(size_t)row * QKVSTR + col];
#pragma unroll
  for (int j = 0; j < 8; ++j) {
    float fa = __uint_as_float((unsigned)(unsigned short)a.u[j] << 16);
    float fb = __uint_as_float((unsigned)(unsigned short)b.u[j] << 16);
    o.u[j] = f2bf(fa * w0 + fb * w1);
  }
  *(uint4v*)&A[(size_t)row * DIM + col] = o.v;
}

extern "C" void kernel_launch(void* const* d_in, const int* in_sizes, int n_in,
                              void* d_out, int out_size, void* d_ws, size_t ws_size,
                              hipStream_t stream) {
  (void)in_sizes; (void)n_in; (void)out_size; (void)ws_size;
  const float* X  = (const float*)d_in[0];
  const float* wq = (const float*)d_in[1];
  const float* bq = (const float*)d_in[2];
  const float* wk = (const float*)d_in[3];
  const float* wv = (const float*)d_in[4];
  const float* bv = (const float*)d_in[5];
  const float* wo = (const float*)d_in[6];
  const float* bo = (const float*)d_in[7];

  char* ws = (char*)d_ws;
  const size_t SZ_XD  = (size_t)SEQ * DIM * 2;      // 8 MB
  const size_t SZ_W   = (size_t)DIM * DIM * 2;      // 2 MB
  const size_t SZ_QKV = (size_t)SEQ * QKVSTR * 2;   // 24 MB
  unsigned short* Xb   = (unsigned short*)(ws);                    // dead after QKV gemm -> Opart0/Ab
  unsigned short* Wqkv = (unsigned short*)(ws + SZ_XD);            // dead after QKV gemm -> Lg
  unsigned short* Wob  = (unsigned short*)(ws + SZ_XD + 3 * SZ_W);
  unsigned short* QKVb = (unsigned short*)(ws + SZ_XD + 4 * SZ_W); // [4096][3072]
  unsigned short* Vtb  = (unsigned short*)(ws + SZ_XD + 4 * SZ_W + SZ_QKV);
  unsigned short* Ab   = Xb;
  float*          Lg   = (float*)Wqkv;               // [2][NH][SEQ] f32 = 512 KB

  const float QSCALE = 0.125f * 1.44269504088896f;  // fold 1/sqrt(hd) * log2(e) into Wq/bq

  // one fused cast launch: 1048576 groups of 8 -> 4096 blocks
  cast_all_kernel<<<4096, 256, 0, stream>>>(X, wq, wk, wv, wo, Xb, Wqkv, Wob, QSCALE);

  // fused QKV projection: [4096][3072] bf16
  gemm_bt_kernel<1, 0><<<dim3(QKVSTR / 128, SEQ / 128), 256, 0, stream>>>(
      Xb, Wqkv, bq, bv, QSCALE, QKVb, SEQ, QKVSTR, DIM);

  // V^T: [1024][4096]
  transpose_kernel<<<dim3(SEQ / 64, DIM / 64), 256, 0, stream>>>(QKVb + 2 * DIM, Vtb);

  // kv-split attention: partial0 -> Ab(Xb), partial1 -> QKVb dead V-cols, l -> Lg
  attn_kernel<<<SEQ / 128 * NH * 2, 256, 0, stream>>>(QKVb, Vtb, Ab, QKVb + 2 * DIM, Lg);

  // exact combine (no-max softmax partials), in-place into Ab
  combine_kernel<<<SEQ * DIM / 8 / 256, 256, 0, stream>>>(Ab, QKVb + 2 * DIM, Lg);

  // output projection (f32 out)
  gemm_bt_kernel<2, 1><<<dim3(DIM / 128, SEQ / 128), 256, 0, stream>>>(
      Ab, Wob, bo, nullptr, 1.f, d_out, SEQ, DIM, DIM);
}

// Round 9
// 170.025 us; speedup vs baseline: 1.7532x; 1.0338x over previous
//
#include <hip/hip_runtime.h>

#define SEQ 4096
#define DIM 1024
#define NH 16
#define HD 64
#define QKVSTR 3072

typedef __attribute__((ext_vector_type(8))) short bf16x8;
typedef __attribute__((ext_vector_type(4))) float f32x4;
typedef __attribute__((ext_vector_type(16))) float f32x16;
typedef __attribute__((ext_vector_type(4))) unsigned int uint4v;

__device__ __forceinline__ unsigned short f2bf(float f) {
  unsigned int b = __float_as_uint(f);
  b = b + 0x7fffu + ((b >> 16) & 1u);
  return (unsigned short)(b >> 16);
}

__device__ __forceinline__ unsigned int cvt_pk_bf16(float lo, float hi) {
  unsigned int r;
  asm("v_cvt_pk_bf16_f32 %0, %1, %2" : "=v"(r) : "v"(lo), "v"(hi));
  return r;
}

__device__ __forceinline__ float fast_exp2(float x) {
#if __has_builtin(__builtin_amdgcn_exp2f)
  return __builtin_amdgcn_exp2f(x);
#else
  float r; asm("v_exp_f32 %0, %1" : "=v"(r) : "v"(x)); return r;
#endif
}

typedef __attribute__((address_space(3))) unsigned int lds_uint;
typedef __attribute__((address_space(1))) const unsigned int global_uint;

__device__ __forceinline__ void gload_lds16(const void* g, void* l) {
  __builtin_amdgcn_global_load_lds((global_uint*)g, (lds_uint*)l, 16, 0, 0);
}

// ---------------- fused cast fp32 -> bf16 for all 5 tensors (1 launch) ----------------
__global__ __launch_bounds__(256) void cast_all_kernel(
    const float* __restrict__ X, const float* __restrict__ wq, const float* __restrict__ wk,
    const float* __restrict__ wv, const float* __restrict__ wo,
    unsigned short* __restrict__ Xb, unsigned short* __restrict__ Wqkv,
    unsigned short* __restrict__ Wob, float qscale) {
  int i = blockIdx.x * 256 + threadIdx.x;
  const float* src;
  unsigned short* dst;
  float sc = 1.f;
  if (i < 524288) { src = X + (size_t)i * 8; dst = Xb + (size_t)i * 8; }
  else if (i < 655360) { int j = i - 524288; src = wq + (size_t)j * 8; dst = Wqkv + (size_t)j * 8; sc = qscale; }
  else if (i < 786432) { int j = i - 655360; src = wk + (size_t)j * 8; dst = Wqkv + 1048576 + (size_t)j * 8; }
  else if (i < 917504) { int j = i - 786432; src = wv + (size_t)j * 8; dst = Wqkv + 2097152 + (size_t)j * 8; }
  else { int j = i - 917504; src = wo + (size_t)j * 8; dst = Wob + (size_t)j * 8; }
  const float4* p = (const float4*)src;
  float4 x0 = p[0], x1 = p[1];
  union { unsigned short u[8]; uint4v v; } o;
  o.u[0] = f2bf(x0.x * sc); o.u[1] = f2bf(x0.y * sc);
  o.u[2] = f2bf(x0.z * sc); o.u[3] = f2bf(x0.w * sc);
  o.u[4] = f2bf(x1.x * sc); o.u[5] = f2bf(x1.y * sc);
  o.u[6] = f2bf(x1.z * sc); o.u[7] = f2bf(x1.w * sc);
  *(uint4v*)dst = o.v;
}

// ---------------- GEMM: C[M,N] = A[M,K](bf16) @ B[N,K]^T(bf16) (+bias) ----------------
// T1: bijective XCD swizzle on flattened block id (nwg % 8 == 0 for all uses).
template<int BIASMODE, int OUT_F32>
__global__ __launch_bounds__(256) void gemm_bt_kernel(
    const unsigned short* __restrict__ A, const unsigned short* __restrict__ B,
    const float* __restrict__ b0, const float* __restrict__ b1, float qscale,
    void* __restrict__ Cout, int M, int N, int K) {
  __shared__ unsigned short As[128 * 32];
  __shared__ unsigned short Bs[128 * 32];
  int tid = threadIdx.x;
  int wave = tid >> 6, lane = tid & 63;
  int g = lane >> 4, lc = lane & 15;
  int wm = wave >> 1, wn = wave & 1;

  int gx = gridDim.x;
  int wgid = blockIdx.y * gx + blockIdx.x;
  int cpx = (gx * gridDim.y) >> 3;
  int sw = (wgid & 7) * cpx + (wgid >> 3);
  int m0 = (sw / gx) * 128, n0 = (sw % gx) * 128;

  f32x4 acc[4][4] = {};

  for (int k0 = 0; k0 < K; k0 += 32) {
    __syncthreads();
    for (int c = 0; c < 2; ++c) {
      int chunk = c * 256 + wave * 64 + lane;
      int row = chunk >> 2, cb = chunk & 3;
      gload_lds16(A + (size_t)(m0 + row) * K + k0 + cb * 8, As + (c * 256 + wave * 64) * 8);
      gload_lds16(B + (size_t)(n0 + row) * K + k0 + cb * 8, Bs + (c * 256 + wave * 64) * 8);
    }
    __syncthreads();
    bf16x8 af[4], bfr[4];
    for (int mf = 0; mf < 4; ++mf)
      af[mf] = *(const bf16x8*)&As[(wm * 64 + mf * 16 + lc) * 32 + g * 8];
    for (int nf = 0; nf < 4; ++nf)
      bfr[nf] = *(const bf16x8*)&Bs[(wn * 64 + nf * 16 + lc) * 32 + g * 8];
    for (int mf = 0; mf < 4; ++mf)
      for (int nf = 0; nf < 4; ++nf)
        acc[mf][nf] = __builtin_amdgcn_mfma_f32_16x16x32_bf16(af[mf], bfr[nf], acc[mf][nf], 0, 0, 0);
  }

  for (int nf = 0; nf < 4; ++nf) {
    int col = n0 + wn * 64 + nf * 16 + lc;
    float bias = 0.f;
    if (BIASMODE == 1) {
      int sect = col >> 10, cc = col & 1023;
      bias = (sect == 0) ? b0[cc] * qscale : ((sect == 2) ? b1[cc] : 0.f);
    } else if (BIASMODE == 2) {
      bias = b0[col];
    }
    for (int mf = 0; mf < 4; ++mf) {
      int row = m0 + wm * 64 + mf * 16 + g * 4;
      for (int r = 0; r < 4; ++r) {
        float v = acc[mf][nf][r] + bias;
        if (OUT_F32) ((float*)Cout)[(size_t)(row + r) * N + col] = v;
        else ((unsigned short*)Cout)[(size_t)(row + r) * N + col] = f2bf(v);
      }
    }
  }
}

// ---------------- V transpose: V (rows of QKV, stride 3072) -> Vt[D][S] ----------------
__global__ __launch_bounds__(256) void transpose_kernel(
    const unsigned short* __restrict__ V, unsigned short* __restrict__ Vt) {
  __shared__ unsigned short Ts[64 * 72];
  int tid = threadIdx.x;
  int s0 = blockIdx.x * 64, d0 = blockIdx.y * 64;
  for (int c = 0; c < 2; ++c) {
    int q = c * 256 + tid;
    int r = q >> 3, cb = q & 7;
    uint4v v = *(const uint4v*)&V[(size_t)(s0 + r) * QKVSTR + d0 + cb * 8];
    *(uint4v*)&Ts[r * 72 + cb * 8] = v;
  }
  __syncthreads();
  for (int c = 0; c < 2; ++c) {
    int q = c * 256 + tid;
    int d = q >> 3, sc = q & 7;
    union { unsigned short u[8]; uint4v v; } ov;
    for (int j = 0; j < 8; ++j) ov.u[j] = Ts[(sc * 8 + j) * 72 + d];
    *(uint4v*)&Vt[(size_t)(d0 + d) * SEQ + s0 + sc * 8] = ov.v;
  }
}

// ---------------- flash attention, swapped-QK 32x32, counted-vmcnt pipeline ----------------
// R6-proven sync skeleton (2 bufs, 2 barriers/tile, vmcnt(4) never 0).
// New: row-sum via MFMA against a ones-fragment (removes 32 VALU adds/tile;
// extraction via 32-float LDS slice at end), hoisted offb[] frag addressing.
__global__ __launch_bounds__(256) void attn_kernel(
    const unsigned short* __restrict__ QKV, const unsigned short* __restrict__ Vt,
    unsigned short* __restrict__ Aout) {
  __shared__ unsigned short Qs[128 * 64];
  __shared__ unsigned short Ks[2][64 * 64];
  __shared__ unsigned short Vs[2][64 * 64];
  int tid = threadIdx.x;
  int w = tid >> 6, lane = tid & 63;
  int hi = lane >> 5, l31 = lane & 31;

  // XCD swizzle: 512 blocks, 8 XCDs -> XCD x owns heads 2x..2x+1 (K/V fit 4MB L2)
  int bid = blockIdx.x;
  int swz = (bid & 7) * 64 + (bid >> 3);
  int h = swz >> 5;
  int q0 = (swz & 31) * 128;

  const unsigned short* Qg = QKV + h * HD;
  const unsigned short* Kg = QKV + DIM + h * HD;
  const unsigned short* Vg = Vt + (size_t)(h * HD) * SEQ;

  // loop-invariant per-lane staging offsets (chunk = c*256 + w*64 + lane)
  int ch0 = w * 64 + lane;
  int r0s = ch0 >> 3, d0s = (ch0 & 7) ^ (r0s & 7);
  int ch1 = 256 + ch0;
  int r1s = ch1 >> 3, d1s = (ch1 & 7) ^ (r1s & 7);
  size_t koff0 = (size_t)r0s * QKVSTR + d0s * 8;
  size_t koff1 = (size_t)r1s * QKVSTR + d1s * 8;
  size_t voff0 = (size_t)r0s * SEQ + d0s * 8;
  size_t voff1 = (size_t)r1s * SEQ + d1s * 8;
  unsigned short* ldsK_lo[2] = { &Ks[0][(w * 64) * 8],       &Ks[1][(w * 64) * 8] };
  unsigned short* ldsK_hi[2] = { &Ks[0][(256 + w * 64) * 8], &Ks[1][(256 + w * 64) * 8] };
  unsigned short* ldsV_lo[2] = { &Vs[0][(w * 64) * 8],       &Vs[1][(w * 64) * 8] };
  unsigned short* ldsV_hi[2] = { &Vs[0][(256 + w * 64) * 8], &Vs[1][(256 + w * 64) * 8] };

  // stage Q [128][64], XOR-swizzled via pre-swizzled global source (4 loads)
  for (int c = 0; c < 4; ++c) {
    int chunk = c * 256 + w * 64 + lane;
    int row = chunk >> 3, pos = chunk & 7;
    int db = pos ^ (row & 7);
    gload_lds16(Qg + (size_t)(q0 + row) * QKVSTR + db * 8, Qs + (c * 256 + w * 64) * 8);
  }
  // stage K/V tile 0 (4 loads) -> 8 outstanding
  gload_lds16(Kg + koff0, ldsK_lo[0]);
  gload_lds16(Kg + koff1, ldsK_hi[0]);
  gload_lds16(Vg + voff0, ldsV_lo[0]);
  gload_lds16(Vg + voff1, ldsV_hi[0]);
  asm volatile("s_waitcnt vmcnt(4)" ::: "memory");  // Q done; tile0 in flight
  __builtin_amdgcn_sched_barrier(0);
  __builtin_amdgcn_s_barrier();

  // Q fragments in registers (B-operand: col q = l31, k = d)
  bf16x8 qf[4];
  {
    int qrow = w * 32 + l31;
    for (int dc = 0; dc < 4; ++dc) {
      int pos = 2 * dc + hi;
      qf[dc] = *(const bf16x8*)&Qs[qrow * 64 + (pos ^ (qrow & 7)) * 8];
    }
  }

  // hoisted frag byte offsets (f=1 row+32 keeps &7 -> +4096B immediate)
  int offb[4];
#pragma unroll
  for (int dc = 0; dc < 4; ++dc)
    offb[dc] = l31 * 128 + (((2 * dc + hi) ^ (l31 & 7)) * 16);
  const char* KbA = (const char*)&Ks[0][0];
  const char* KbB = (const char*)&Ks[1][0];
  const char* VbA = (const char*)&Vs[0][0];
  const char* VbB = (const char*)&Vs[1][0];

  // ones fragment for row-sum MFMA
  union { unsigned short us[8]; bf16x8 v; } one8;
#pragma unroll
  for (int j = 0; j < 8; ++j) one8.us[j] = 0x3F80;  // bf16 1.0

  f32x16 o0 = {}, o1 = {}, lsa = {};
  int cur = 0;

  for (int t = 0; t < SEQ / 64; ++t) {
    // prefetch tile t+1 (wraps to 0 on last iter to keep vmcnt invariant)
    {
      int kvn = ((t + 1) & (SEQ / 64 - 1)) * 64;
      const unsigned short* Kt = Kg + (size_t)kvn * QKVSTR;
      const unsigned short* Vtt = Vg + kvn;
      int nb = cur ^ 1;
      gload_lds16(Kt + koff0, ldsK_lo[nb]);
      gload_lds16(Kt + koff1, ldsK_hi[nb]);
      gload_lds16(Vtt + voff0, ldsV_lo[nb]);
      gload_lds16(Vtt + voff1, ldsV_hi[nb]);
    }
    asm volatile("s_waitcnt vmcnt(4)" ::: "memory");  // tile t resident (ours)
    __builtin_amdgcn_sched_barrier(0);
    __builtin_amdgcn_s_barrier();                     // tile t resident (all waves)
    __builtin_amdgcn_sched_barrier(0);

    const char* Kb = cur ? KbB : KbA;
    const char* Vb = cur ? VbB : VbA;

    // K fragments (A-operand: row kv = f*32+l31, k = d)
    bf16x8 kf0[4], kf1[4];
#pragma unroll
    for (int dc = 0; dc < 4; ++dc) {
      kf0[dc] = *(const bf16x8*)(Kb + offb[dc]);
      kf1[dc] = *(const bf16x8*)(Kb + offb[dc] + 4096);
    }
    f32x16 st0 = {}, st1 = {};
    __builtin_amdgcn_s_setprio(1);
#pragma unroll
    for (int dc = 0; dc < 4; ++dc) {
      st0 = __builtin_amdgcn_mfma_f32_32x32x16_bf16(kf0[dc], qf[dc], st0, 0, 0, 0);
      st1 = __builtin_amdgcn_mfma_f32_32x32x16_bf16(kf1[dc], qf[dc], st1, 0, 0, 0);
    }
    __builtin_amdgcn_s_setprio(0);

    // V fragments early (latency hides under exp/pack)
    bf16x8 vf0[4], vf1[4];
#pragma unroll
    for (int c = 0; c < 4; ++c) {
      vf0[c] = *(const bf16x8*)(Vb + offb[c]);
      vf1[c] = *(const bf16x8*)(Vb + offb[c] + 4096);
    }

    // P = exp2(S^T) in-register (no scalar row-sum: MFMA handles it)
    float p0[16], p1[16];
#pragma unroll
    for (int r = 0; r < 16; ++r) p0[r] = fast_exp2(st0[r]);
#pragma unroll
    for (int r = 0; r < 16; ++r) p1[r] = fast_exp2(st1[r]);

    // pack to bf16 + permlane32_swap -> PV A-frags pa[c] (T12)
    bf16x8 pa[4];
#pragma unroll
    for (int f = 0; f < 2; ++f) {
      const float* pp = f ? p1 : p0;
#pragma unroll
      for (int cc = 0; cc < 2; ++cc) {
        unsigned uLO0 = cvt_pk_bf16(pp[8 * cc + 0], pp[8 * cc + 1]);
        unsigned uLO1 = cvt_pk_bf16(pp[8 * cc + 2], pp[8 * cc + 3]);
        unsigned uHI0 = cvt_pk_bf16(pp[8 * cc + 4], pp[8 * cc + 5]);
        unsigned uHI1 = cvt_pk_bf16(pp[8 * cc + 6], pp[8 * cc + 7]);
        auto s0 = __builtin_amdgcn_permlane32_swap(uLO0, uHI0, false, false);
        auto s1 = __builtin_amdgcn_permlane32_swap(uLO1, uHI1, false, false);
        union { unsigned u[4]; bf16x8 v; } pw;
        pw.u[0] = s0[0]; pw.u[1] = s1[0]; pw.u[2] = s0[1]; pw.u[3] = s1[1];
        pa[f * 2 + cc] = pw.v;
      }
    }

    // PV + row-sum (lsa = P @ ones, full kv coverage via c=0..3)
    __builtin_amdgcn_s_setprio(1);
#pragma unroll
    for (int c = 0; c < 4; ++c) {
      o0 = __builtin_amdgcn_mfma_f32_32x32x16_bf16(pa[c], vf0[c], o0, 0, 0, 0);
      o1 = __builtin_amdgcn_mfma_f32_32x32x16_bf16(pa[c], vf1[c], o1, 0, 0, 0);
      lsa = __builtin_amdgcn_mfma_f32_32x32x16_bf16(pa[c], one8.v, lsa, 0, 0, 0);
    }
    __builtin_amdgcn_s_setprio(0);

    asm volatile("" ::: "memory");
    __builtin_amdgcn_sched_barrier(0);
    __builtin_amdgcn_s_barrier();   // all reads of tile t done -> next stage may overwrite
    cur ^= 1;
  }

  // extract row-sums: lsa C-frag row R=(r&3)+8*(r>>2)+4*hi (cols identical).
  // lane l31==0 of each half writes its 16 rows; all lanes read row l31.
  // Same-wave DS ordering; Qs is dead. Each wave owns floats [w*32, w*32+32).
  float* Qf = (float*)Qs;
  if (l31 == 0) {
#pragma unroll
    for (int r = 0; r < 16; ++r)
      Qf[w * 32 + ((r & 3) + 8 * (r >> 2) + 4 * hi)] = lsa[r];
  }
  float inv = 1.f / Qf[w * 32 + l31];  // valid for q = l31 (both halves)
#pragma unroll
  for (int r = 0; r < 16; ++r) {
    int qr = (r & 3) + 8 * (r >> 2) + 4 * hi;
    float ir = __shfl(inv, qr + (lane & 32));
    size_t row = q0 + w * 32 + qr;
    Aout[row * DIM + h * HD + l31]      = f2bf(o0[r] * ir);
    Aout[row * DIM + h * HD + 32 + l31] = f2bf(o1[r] * ir);
  }
}

extern "C" void kernel_launch(void* const* d_in, const int* in_sizes, int n_in,
                              void* d_out, int out_size, void* d_ws, size_t ws_size,
                              hipStream_t stream) {
  (void)in_sizes; (void)n_in; (void)out_size; (void)ws_size;
  const float* X  = (const float*)d_in[0];
  const float* wq = (const float*)d_in[1];
  const float* bq = (const float*)d_in[2];
  const float* wk = (const float*)d_in[3];
  const float* wv = (const float*)d_in[4];
  const float* bv = (const float*)d_in[5];
  const float* wo = (const float*)d_in[6];
  const float* bo = (const float*)d_in[7];

  char* ws = (char*)d_ws;
  const size_t SZ_XD  = (size_t)SEQ * DIM * 2;      // 8 MB
  const size_t SZ_W   = (size_t)DIM * DIM * 2;      // 2 MB
  const size_t SZ_QKV = (size_t)SEQ * QKVSTR * 2;   // 24 MB
  unsigned short* Xb   = (unsigned short*)(ws);                    // reused as Ab
  unsigned short* Wqkv = (unsigned short*)(ws + SZ_XD);            // [3072][1024]
  unsigned short* Wob  = (unsigned short*)(ws + SZ_XD + 3 * SZ_W);
  unsigned short* QKVb = (unsigned short*)(ws + SZ_XD + 4 * SZ_W); // [4096][3072]
  unsigned short* Vtb  = (unsigned short*)(ws + SZ_XD + 4 * SZ_W + SZ_QKV);
  unsigned short* Ab   = Xb;

  const float QSCALE = 0.125f * 1.44269504088896f;  // fold 1/sqrt(hd) * log2(e) into Wq/bq

  // one fused cast launch: 1048576 groups of 8 -> 4096 blocks
  cast_all_kernel<<<4096, 256, 0, stream>>>(X, wq, wk, wv, wo, Xb, Wqkv, Wob, QSCALE);

  // fused QKV projection: [4096][3072] bf16
  gemm_bt_kernel<1, 0><<<dim3(QKVSTR / 128, SEQ / 128), 256, 0, stream>>>(
      Xb, Wqkv, bq, bv, QSCALE, QKVb, SEQ, QKVSTR, DIM);

  // V^T: [1024][4096]
  transpose_kernel<<<dim3(SEQ / 64, DIM / 64), 256, 0, stream>>>(QKVb + 2 * DIM, Vtb);

  attn_kernel<<<SEQ / 128 * NH, 256, 0, stream>>>(QKVb, Vtb, Ab);

  // output projection (f32 out)
  gemm_bt_kernel<2, 1><<<dim3(DIM / 128, SEQ / 128), 256, 0, stream>>>(
      Ab, Wob, bo, nullptr, 1.f, d_out, SEQ, DIM, DIM);
}

// Round 10
// 167.289 us; speedup vs baseline: 1.7818x; 1.0164x over previous
//
#include <hip/hip_runtime.h>

#define SEQ 4096
#define DIM 1024
#define NH 16
#define HD 64
#define QKVSTR 3072

typedef __attribute__((ext_vector_type(8))) short bf16x8;
typedef __attribute__((ext_vector_type(4))) float f32x4;
typedef __attribute__((ext_vector_type(16))) float f32x16;
typedef __attribute__((ext_vector_type(4))) unsigned int uint4v;

__device__ __forceinline__ unsigned short f2bf(float f) {
  unsigned int b = __float_as_uint(f);
  b = b + 0x7fffu + ((b >> 16) & 1u);
  return (unsigned short)(b >> 16);
}

__device__ __forceinline__ unsigned int cvt_pk_bf16(float lo, float hi) {
  unsigned int r;
  asm("v_cvt_pk_bf16_f32 %0, %1, %2" : "=v"(r) : "v"(lo), "v"(hi));
  return r;
}

__device__ __forceinline__ float fast_exp2(float x) {
#if __has_builtin(__builtin_amdgcn_exp2f)
  return __builtin_amdgcn_exp2f(x);
#else
  float r; asm("v_exp_f32 %0, %1" : "=v"(r) : "v"(x)); return r;
#endif
}

typedef __attribute__((address_space(3))) unsigned int lds_uint;
typedef __attribute__((address_space(1))) const unsigned int global_uint;

__device__ __forceinline__ void gload_lds16(const void* g, void* l) {
  __builtin_amdgcn_global_load_lds((global_uint*)g, (lds_uint*)l, 16, 0, 0);
}

// ---------------- fused cast fp32 -> bf16 for all 5 tensors (1 launch) ----------------
__global__ __launch_bounds__(256) void cast_all_kernel(
    const float* __restrict__ X, const float* __restrict__ wq, const float* __restrict__ wk,
    const float* __restrict__ wv, const float* __restrict__ wo,
    unsigned short* __restrict__ Xb, unsigned short* __restrict__ Wqkv,
    unsigned short* __restrict__ Wob, float qscale) {
  int i = blockIdx.x * 256 + threadIdx.x;
  const float* src;
  unsigned short* dst;
  float sc = 1.f;
  if (i < 524288) { src = X + (size_t)i * 8; dst = Xb + (size_t)i * 8; }
  else if (i < 655360) { int j = i - 524288; src = wq + (size_t)j * 8; dst = Wqkv + (size_t)j * 8; sc = qscale; }
  else if (i < 786432) { int j = i - 655360; src = wk + (size_t)j * 8; dst = Wqkv + 1048576 + (size_t)j * 8; }
  else if (i < 917504) { int j = i - 786432; src = wv + (size_t)j * 8; dst = Wqkv + 2097152 + (size_t)j * 8; }
  else { int j = i - 917504; src = wo + (size_t)j * 8; dst = Wob + (size_t)j * 8; }
  const float4* p = (const float4*)src;
  float4 x0 = p[0], x1 = p[1];
  union { unsigned short u[8]; uint4v v; } o;
  o.u[0] = f2bf(x0.x * sc); o.u[1] = f2bf(x0.y * sc);
  o.u[2] = f2bf(x0.z * sc); o.u[3] = f2bf(x0.w * sc);
  o.u[4] = f2bf(x1.x * sc); o.u[5] = f2bf(x1.y * sc);
  o.u[6] = f2bf(x1.z * sc); o.u[7] = f2bf(x1.w * sc);
  *(uint4v*)dst = o.v;
}

// ---------------- GEMM: C[M,N] = A[M,K](bf16) @ B[N,K]^T(bf16) (+bias) ----------------
// T3-minimum 2-phase: stage tile t+1 BEFORE computing tile t; counted vmcnt(4)
// keeps prefetch in flight across raw barriers (attn-proven sync skeleton).
// T1: bijective XCD swizzle on flattened block id (nwg % 8 == 0 for all uses).
template<int BIASMODE, int OUT_F32>
__global__ __launch_bounds__(256) void gemm_bt_kernel(
    const unsigned short* __restrict__ A, const unsigned short* __restrict__ B,
    const float* __restrict__ b0, const float* __restrict__ b1, float qscale,
    void* __restrict__ Cout, int M, int N, int K) {
  __shared__ unsigned short As[2][128 * 32];
  __shared__ unsigned short Bs[2][128 * 32];
  int tid = threadIdx.x;
  int wave = tid >> 6, lane = tid & 63;
  int g = lane >> 4, lc = lane & 15;
  int wm = wave >> 1, wn = wave & 1;

  int gx = gridDim.x;
  int wgid = blockIdx.y * gx + blockIdx.x;
  int cpx = (gx * gridDim.y) >> 3;
  int sw = (wgid & 7) * cpx + (wgid >> 3);
  int m0 = (sw / gx) * 128, n0 = (sw % gx) * 128;

  // per-lane staging geometry (chunk = c*256 + wave*64 + lane; c = 0,1)
  int ch0 = wave * 64 + lane;
  int r0 = ch0 >> 2, cb0 = ch0 & 3;
  int ch1 = 256 + ch0;
  int r1 = ch1 >> 2, cb1 = ch1 & 3;
  const unsigned short* Ar0 = A + (size_t)(m0 + r0) * K + cb0 * 8;
  const unsigned short* Ar1 = A + (size_t)(m0 + r1) * K + cb1 * 8;
  const unsigned short* Br0 = B + (size_t)(n0 + r0) * K + cb0 * 8;
  const unsigned short* Br1 = B + (size_t)(n0 + r1) * K + cb1 * 8;
  unsigned short* sAlo[2] = { &As[0][(wave * 64) * 8],       &As[1][(wave * 64) * 8] };
  unsigned short* sAhi[2] = { &As[0][(256 + wave * 64) * 8], &As[1][(256 + wave * 64) * 8] };
  unsigned short* sBlo[2] = { &Bs[0][(wave * 64) * 8],       &Bs[1][(wave * 64) * 8] };
  unsigned short* sBhi[2] = { &Bs[0][(256 + wave * 64) * 8], &Bs[1][(256 + wave * 64) * 8] };

  f32x4 acc[4][4] = {};

  // prologue: stage K-step 0 into buffer 0 (4 loads in flight)
  gload_lds16(Ar0, sAlo[0]);
  gload_lds16(Ar1, sAhi[0]);
  gload_lds16(Br0, sBlo[0]);
  gload_lds16(Br1, sBhi[0]);

  int cur = 0;
  for (int k0 = 0; k0 < K; k0 += 32) {
    // stage K-step t+1 (wraps to 0 on last iter to keep vmcnt invariant)
    {
      int kn = (k0 + 32 < K) ? (k0 + 32) : 0;
      int nb = cur ^ 1;
      gload_lds16(Ar0 + kn, sAlo[nb]);
      gload_lds16(Ar1 + kn, sAhi[nb]);
      gload_lds16(Br0 + kn, sBlo[nb]);
      gload_lds16(Br1 + kn, sBhi[nb]);
    }
    asm volatile("s_waitcnt vmcnt(4)" ::: "memory");  // tile t resident (ours)
    __builtin_amdgcn_sched_barrier(0);
    __builtin_amdgcn_s_barrier();                     // tile t resident (all waves)
    __builtin_amdgcn_sched_barrier(0);

    bf16x8 af[4], bfr[4];
    for (int mf = 0; mf < 4; ++mf)
      af[mf] = *(const bf16x8*)&As[cur][(wm * 64 + mf * 16 + lc) * 32 + g * 8];
    for (int nf = 0; nf < 4; ++nf)
      bfr[nf] = *(const bf16x8*)&Bs[cur][(wn * 64 + nf * 16 + lc) * 32 + g * 8];
    for (int mf = 0; mf < 4; ++mf)
      for (int nf = 0; nf < 4; ++nf)
        acc[mf][nf] = __builtin_amdgcn_mfma_f32_16x16x32_bf16(af[mf], bfr[nf], acc[mf][nf], 0, 0, 0);

    asm volatile("" ::: "memory");
    __builtin_amdgcn_sched_barrier(0);
    __builtin_amdgcn_s_barrier();   // all reads of tile t done -> next stage may overwrite
    cur ^= 1;
  }

  for (int nf = 0; nf < 4; ++nf) {
    int col = n0 + wn * 64 + nf * 16 + lc;
    float bias = 0.f;
    if (BIASMODE == 1) {
      int sect = col >> 10, cc = col & 1023;
      bias = (sect == 0) ? b0[cc] * qscale : ((sect == 2) ? b1[cc] : 0.f);
    } else if (BIASMODE == 2) {
      bias = b0[col];
    }
    for (int mf = 0; mf < 4; ++mf) {
      int row = m0 + wm * 64 + mf * 16 + g * 4;
      for (int r = 0; r < 4; ++r) {
        float v = acc[mf][nf][r] + bias;
        if (OUT_F32) ((float*)Cout)[(size_t)(row + r) * N + col] = v;
        else ((unsigned short*)Cout)[(size_t)(row + r) * N + col] = f2bf(v);
      }
    }
  }
}

// ---------------- V transpose: V (rows of QKV, stride 3072) -> Vt[D][S] ----------------
__global__ __launch_bounds__(256) void transpose_kernel(
    const unsigned short* __restrict__ V, unsigned short* __restrict__ Vt) {
  __shared__ unsigned short Ts[64 * 72];
  int tid = threadIdx.x;
  int s0 = blockIdx.x * 64, d0 = blockIdx.y * 64;
  for (int c = 0; c < 2; ++c) {
    int q = c * 256 + tid;
    int r = q >> 3, cb = q & 7;
    uint4v v = *(const uint4v*)&V[(size_t)(s0 + r) * QKVSTR + d0 + cb * 8];
    *(uint4v*)&Ts[r * 72 + cb * 8] = v;
  }
  __syncthreads();
  for (int c = 0; c < 2; ++c) {
    int q = c * 256 + tid;
    int d = q >> 3, sc = q & 7;
    union { unsigned short u[8]; uint4v v; } ov;
    for (int j = 0; j < 8; ++j) ov.u[j] = Ts[(sc * 8 + j) * 72 + d];
    *(uint4v*)&Vt[(size_t)(d0 + d) * SEQ + s0 + sc * 8] = ov.v;
  }
}

// ---------------- flash attention, swapped-QK 32x32, counted-vmcnt pipeline ----------------
// R9-proven body, unchanged: 2 bufs, 2 barriers/tile, vmcnt(4) never 0,
// lsum via MFMA ones-fragment, hoisted offb[] frag addressing.
__global__ __launch_bounds__(256) void attn_kernel(
    const unsigned short* __restrict__ QKV, const unsigned short* __restrict__ Vt,
    unsigned short* __restrict__ Aout) {
  __shared__ unsigned short Qs[128 * 64];
  __shared__ unsigned short Ks[2][64 * 64];
  __shared__ unsigned short Vs[2][64 * 64];
  int tid = threadIdx.x;
  int w = tid >> 6, lane = tid & 63;
  int hi = lane >> 5, l31 = lane & 31;

  // XCD swizzle: 512 blocks, 8 XCDs -> XCD x owns heads 2x..2x+1 (K/V fit 4MB L2)
  int bid = blockIdx.x;
  int swz = (bid & 7) * 64 + (bid >> 3);
  int h = swz >> 5;
  int q0 = (swz & 31) * 128;

  const unsigned short* Qg = QKV + h * HD;
  const unsigned short* Kg = QKV + DIM + h * HD;
  const unsigned short* Vg = Vt + (size_t)(h * HD) * SEQ;

  // loop-invariant per-lane staging offsets (chunk = c*256 + w*64 + lane)
  int ch0 = w * 64 + lane;
  int r0s = ch0 >> 3, d0s = (ch0 & 7) ^ (r0s & 7);
  int ch1 = 256 + ch0;
  int r1s = ch1 >> 3, d1s = (ch1 & 7) ^ (r1s & 7);
  size_t koff0 = (size_t)r0s * QKVSTR + d0s * 8;
  size_t koff1 = (size_t)r1s * QKVSTR + d1s * 8;
  size_t voff0 = (size_t)r0s * SEQ + d0s * 8;
  size_t voff1 = (size_t)r1s * SEQ + d1s * 8;
  unsigned short* ldsK_lo[2] = { &Ks[0][(w * 64) * 8],       &Ks[1][(w * 64) * 8] };
  unsigned short* ldsK_hi[2] = { &Ks[0][(256 + w * 64) * 8], &Ks[1][(256 + w * 64) * 8] };
  unsigned short* ldsV_lo[2] = { &Vs[0][(w * 64) * 8],       &Vs[1][(w * 64) * 8] };
  unsigned short* ldsV_hi[2] = { &Vs[0][(256 + w * 64) * 8], &Vs[1][(256 + w * 64) * 8] };

  // stage Q [128][64], XOR-swizzled via pre-swizzled global source (4 loads)
  for (int c = 0; c < 4; ++c) {
    int chunk = c * 256 + w * 64 + lane;
    int row = chunk >> 3, pos = chunk & 7;
    int db = pos ^ (row & 7);
    gload_lds16(Qg + (size_t)(q0 + row) * QKVSTR + db * 8, Qs + (c * 256 + w * 64) * 8);
  }
  // stage K/V tile 0 (4 loads) -> 8 outstanding
  gload_lds16(Kg + koff0, ldsK_lo[0]);
  gload_lds16(Kg + koff1, ldsK_hi[0]);
  gload_lds16(Vg + voff0, ldsV_lo[0]);
  gload_lds16(Vg + voff1, ldsV_hi[0]);
  asm volatile("s_waitcnt vmcnt(4)" ::: "memory");  // Q done; tile0 in flight
  __builtin_amdgcn_sched_barrier(0);
  __builtin_amdgcn_s_barrier();

  // Q fragments in registers (B-operand: col q = l31, k = d)
  bf16x8 qf[4];
  {
    int qrow = w * 32 + l31;
    for (int dc = 0; dc < 4; ++dc) {
      int pos = 2 * dc + hi;
      qf[dc] = *(const bf16x8*)&Qs[qrow * 64 + (pos ^ (qrow & 7)) * 8];
    }
  }

  // hoisted frag byte offsets (f=1 row+32 keeps &7 -> +4096B immediate)
  int offb[4];
#pragma unroll
  for (int dc = 0; dc < 4; ++dc)
    offb[dc] = l31 * 128 + (((2 * dc + hi) ^ (l31 & 7)) * 16);
  const char* KbA = (const char*)&Ks[0][0];
  const char* KbB = (const char*)&Ks[1][0];
  const char* VbA = (const char*)&Vs[0][0];
  const char* VbB = (const char*)&Vs[1][0];

  // ones fragment for row-sum MFMA
  union { unsigned short us[8]; bf16x8 v; } one8;
#pragma unroll
  for (int j = 0; j < 8; ++j) one8.us[j] = 0x3F80;  // bf16 1.0

  f32x16 o0 = {}, o1 = {}, lsa = {};
  int cur = 0;

  for (int t = 0; t < SEQ / 64; ++t) {
    // prefetch tile t+1 (wraps to 0 on last iter to keep vmcnt invariant)
    {
      int kvn = ((t + 1) & (SEQ / 64 - 1)) * 64;
      const unsigned short* Kt = Kg + (size_t)kvn * QKVSTR;
      const unsigned short* Vtt = Vg + kvn;
      int nb = cur ^ 1;
      gload_lds16(Kt + koff0, ldsK_lo[nb]);
      gload_lds16(Kt + koff1, ldsK_hi[nb]);
      gload_lds16(Vtt + voff0, ldsV_lo[nb]);
      gload_lds16(Vtt + voff1, ldsV_hi[nb]);
    }
    asm volatile("s_waitcnt vmcnt(4)" ::: "memory");  // tile t resident (ours)
    __builtin_amdgcn_sched_barrier(0);
    __builtin_amdgcn_s_barrier();                     // tile t resident (all waves)
    __builtin_amdgcn_sched_barrier(0);

    const char* Kb = cur ? KbB : KbA;
    const char* Vb = cur ? VbB : VbA;

    // K fragments (A-operand: row kv = f*32+l31, k = d)
    bf16x8 kf0[4], kf1[4];
#pragma unroll
    for (int dc = 0; dc < 4; ++dc) {
      kf0[dc] = *(const bf16x8*)(Kb + offb[dc]);
      kf1[dc] = *(const bf16x8*)(Kb + offb[dc] + 4096);
    }
    f32x16 st0 = {}, st1 = {};
    __builtin_amdgcn_s_setprio(1);
#pragma unroll
    for (int dc = 0; dc < 4; ++dc) {
      st0 = __builtin_amdgcn_mfma_f32_32x32x16_bf16(kf0[dc], qf[dc], st0, 0, 0, 0);
      st1 = __builtin_amdgcn_mfma_f32_32x32x16_bf16(kf1[dc], qf[dc], st1, 0, 0, 0);
    }
    __builtin_amdgcn_s_setprio(0);

    // V fragments early (latency hides under exp/pack)
    bf16x8 vf0[4], vf1[4];
#pragma unroll
    for (int c = 0; c < 4; ++c) {
      vf0[c] = *(const bf16x8*)(Vb + offb[c]);
      vf1[c] = *(const bf16x8*)(Vb + offb[c] + 4096);
    }

    // P = exp2(S^T) in-register (row-sum handled by MFMA)
    float p0[16], p1[16];
#pragma unroll
    for (int r = 0; r < 16; ++r) p0[r] = fast_exp2(st0[r]);
#pragma unroll
    for (int r = 0; r < 16; ++r) p1[r] = fast_exp2(st1[r]);

    // pack to bf16 + permlane32_swap -> PV A-frags pa[c] (T12)
    bf16x8 pa[4];
#pragma unroll
    for (int f = 0; f < 2; ++f) {
      const float* pp = f ? p1 : p0;
#pragma unroll
      for (int cc = 0; cc < 2; ++cc) {
        unsigned uLO0 = cvt_pk_bf16(pp[8 * cc + 0], pp[8 * cc + 1]);
        unsigned uLO1 = cvt_pk_bf16(pp[8 * cc + 2], pp[8 * cc + 3]);
        unsigned uHI0 = cvt_pk_bf16(pp[8 * cc + 4], pp[8 * cc + 5]);
        unsigned uHI1 = cvt_pk_bf16(pp[8 * cc + 6], pp[8 * cc + 7]);
        auto s0 = __builtin_amdgcn_permlane32_swap(uLO0, uHI0, false, false);
        auto s1 = __builtin_amdgcn_permlane32_swap(uLO1, uHI1, false, false);
        union { unsigned u[4]; bf16x8 v; } pw;
        pw.u[0] = s0[0]; pw.u[1] = s1[0]; pw.u[2] = s0[1]; pw.u[3] = s1[1];
        pa[f * 2 + cc] = pw.v;
      }
    }

    // PV + row-sum (lsa = P @ ones)
    __builtin_amdgcn_s_setprio(1);
#pragma unroll
    for (int c = 0; c < 4; ++c) {
      o0 = __builtin_amdgcn_mfma_f32_32x32x16_bf16(pa[c], vf0[c], o0, 0, 0, 0);
      o1 = __builtin_amdgcn_mfma_f32_32x32x16_bf16(pa[c], vf1[c], o1, 0, 0, 0);
      lsa = __builtin_amdgcn_mfma_f32_32x32x16_bf16(pa[c], one8.v, lsa, 0, 0, 0);
    }
    __builtin_amdgcn_s_setprio(0);

    asm volatile("" ::: "memory");
    __builtin_amdgcn_sched_barrier(0);
    __builtin_amdgcn_s_barrier();   // all reads of tile t done -> next stage may overwrite
    cur ^= 1;
  }

  // extract row-sums from lsa C-frag via 32-float LDS slice (Qs dead)
  float* Qf = (float*)Qs;
  if (l31 == 0) {
#pragma unroll
    for (int r = 0; r < 16; ++r)
      Qf[w * 32 + ((r & 3) + 8 * (r >> 2) + 4 * hi)] = lsa[r];
  }
  float inv = 1.f / Qf[w * 32 + l31];  // valid for q = l31 (both halves)
#pragma unroll
  for (int r = 0; r < 16; ++r) {
    int qr = (r & 3) + 8 * (r >> 2) + 4 * hi;
    float ir = __shfl(inv, qr + (lane & 32));
    size_t row = q0 + w * 32 + qr;
    Aout[row * DIM + h * HD + l31]      = f2bf(o0[r] * ir);
    Aout[row * DIM + h * HD + 32 + l31] = f2bf(o1[r] * ir);
  }
}

extern "C" void kernel_launch(void* const* d_in, const int* in_sizes, int n_in,
                              void* d_out, int out_size, void* d_ws, size_t ws_size,
                              hipStream_t stream) {
  (void)in_sizes; (void)n_in; (void)out_size; (void)ws_size;
  const float* X  = (const float*)d_in[0];
  const float* wq = (const float*)d_in[1];
  const float* bq = (const float*)d_in[2];
  const float* wk = (const float*)d_in[3];
  const float* wv = (const float*)d_in[4];
  const float* bv = (const float*)d_in[5];
  const float* wo = (const float*)d_in[6];
  const float* bo = (const float*)d_in[7];

  char* ws = (char*)d_ws;
  const size_t SZ_XD  = (size_t)SEQ * DIM * 2;      // 8 MB
  const size_t SZ_W   = (size_t)DIM * DIM * 2;      // 2 MB
  const size_t SZ_QKV = (size_t)SEQ * QKVSTR * 2;   // 24 MB
  unsigned short* Xb   = (unsigned short*)(ws);                    // reused as Ab
  unsigned short* Wqkv = (unsigned short*)(ws + SZ_XD);            // [3072][1024]
  unsigned short* Wob  = (unsigned short*)(ws + SZ_XD + 3 * SZ_W);
  unsigned short* QKVb = (unsigned short*)(ws + SZ_XD + 4 * SZ_W); // [4096][3072]
  unsigned short* Vtb  = (unsigned short*)(ws + SZ_XD + 4 * SZ_W + SZ_QKV);
  unsigned short* Ab   = Xb;

  const float QSCALE = 0.125f * 1.44269504088896f;  // fold 1/sqrt(hd) * log2(e) into Wq/bq

  // one fused cast launch: 1048576 groups of 8 -> 4096 blocks
  cast_all_kernel<<<4096, 256, 0, stream>>>(X, wq, wk, wv, wo, Xb, Wqkv, Wob, QSCALE);

  // fused QKV projection: [4096][3072] bf16
  gemm_bt_kernel<1, 0><<<dim3(QKVSTR / 128, SEQ / 128), 256, 0, stream>>>(
      Xb, Wqkv, bq, bv, QSCALE, QKVb, SEQ, QKVSTR, DIM);

  // V^T: [1024][4096]
  transpose_kernel<<<dim3(SEQ / 64, DIM / 64), 256, 0, stream>>>(QKVb + 2 * DIM, Vtb);

  attn_kernel<<<SEQ / 128 * NH, 256, 0, stream>>>(QKVb, Vtb, Ab);

  // output projection (f32 out)
  gemm_bt_kernel<2, 1><<<dim3(DIM / 128, SEQ / 128), 256, 0, stream>>>(
      Ab, Wob, bo, nullptr, 1.f, d_out, SEQ, DIM, DIM);
}